// Round 5
// baseline (667.420 us; speedup 1.0000x reference)
//
#include <hip/hip_runtime.h>
#include <math.h>

#define BB 4
#define CCH 128
#define HH 384
#define WW 384
constexpr int HW = HH * WW;          // 147456 floats per channel plane

constexpr int TXG = 12;              // float4 groups per block row (48 px)
constexpr int TYR = 16;              // rows per block
constexpr int PR   = 18;             // label/norm tile rows (y0 .. y0+17)
constexpr int NSTR = 56;             // label/norm tile stride; ncol = gx - x0 + 4
#define EPSQ 1e-8f

// 12 forward shifts: (0,1),(0,2),(1,-2..2),(2,-2..2); each unordered pair {p,q}
// once with weight sel(p)+sel(q) == reference's 24 directed shifts.
//
// NO LDS IN THE HOT LOOP: each thread loads its private 3-row x 12-float
// window (9 aligned float4) per channel straight from global, double-buffered
// across channels (XA/XB, all indices compile-time). No barriers, no lgkm
// chains -> 9 independent vmem loads/channel/thread of streaming ILP.
// 3x register-load amplification is served by L1/L2 (neighboring threads'
// windows overlap); unique HBM bytes ~396 MB.
// All address clamps (image edges) only affect window slots whose pairs have
// weight 0: out-of-image q has pk=0, and p rows/cols within 2 of the image
// edge have sel=0, so doPair skips them (w==0).
// Norm sharing is a one-shot epilogue: own norms in registers; tile-edge and
// bottom-halo norms accumulated by edge threads from slots already in their
// windows (tx==0: idx 2,3 = cols x0-2,-1; tx==11: idx 8,9 = cols x0+48,49;
// ty==15: X1/X2 centers = rows y0+16,17). One barrier, then pair epilogue.

__global__ __launch_bounds__(192, 3)
void ctx_main(const float* __restrict__ er, const int* __restrict__ seg,
              const int* __restrict__ gt, float* __restrict__ Ssum,
              int* __restrict__ cntArr, int* __restrict__ bndArr)
{
    __shared__ int   pkT[PR * NSTR];      // 4032 B
    __shared__ float normArr[PR * NSTR];  // 4032 B

    const int tx  = threadIdx.x;          // 0..11
    const int ty  = threadIdx.y;          // 0..15
    const int tid = ty * TXG + tx;
    const int x0  = blockIdx.x * (4 * TXG);   // 48-px tiles
    const int y0  = blockIdx.y * TYR;
    const int b   = blockIdx.z;

    const float* erB = er + (size_t)b * CCH * HW;

    // ---- 9 clamped window offsets (floats), computed once ----
    // window row r covers cols bcol .. bcol+11, bcol = x0 + 4tx - 4
    int off[3][3];
    {
        const int bcol = x0 + 4 * tx - 4;
        #pragma unroll
        for (int r = 0; r < 3; ++r) {
            int gy = y0 + ty + r; if (gy > HH - 1) gy = HH - 1;
            #pragma unroll
            for (int j = 0; j < 3; ++j) {
                int gc = bcol + 4 * j;
                gc = min(max(gc, 0), WW - 4);
                off[r][j] = gy * WW + gc;
            }
        }
    }

    const bool edge = (tx == 0) | (tx == TXG - 1);
    const int  j0   = (tx == 0) ? 2 : 8;          // side-col window slots

    // ---- accumulators ----
    float acc[12][4];
    #pragma unroll
    for (int s = 0; s < 12; ++s)
        #pragma unroll
        for (int i = 0; i < 4; ++i) acc[s][i] = 0.f;
    float nrm[4] = {0.f, 0.f, 0.f, 0.f};
    float ex[2]  = {0.f, 0.f};                    // side-col norms (edge threads)
    float bh0[4] = {0.f, 0.f, 0.f, 0.f};          // row y0+16 center (ty==15)
    float bh1[4] = {0.f, 0.f, 0.f, 0.f};          // row y0+17 center (ty==15)
    float bhe[4] = {0.f, 0.f, 0.f, 0.f};          // bottom corners (ty==15 && edge)

    float XA[3][12], XB[3][12];

    auto LOADW = [&](float (&X)[3][12], int ch) {
        const float* p = erB + (size_t)ch * HW;
        #pragma unroll
        for (int r = 0; r < 3; ++r)
            #pragma unroll
            for (int j = 0; j < 3; ++j)
                *(float4*)&X[r][4 * j] = *(const float4*)(p + off[r][j]);
    };

    auto COMPW = [&](float (&X)[3][12]) {
        #pragma unroll
        for (int i = 0; i < 4; ++i) {
            float f = X[0][4 + i];
            nrm[i]    = fmaf(f, f,           nrm[i]);
            acc[0][i] = fmaf(f, X[0][5 + i], acc[0][i]);   // (0,+1)
            acc[1][i] = fmaf(f, X[0][6 + i], acc[1][i]);   // (0,+2)
            #pragma unroll
            for (int d = 0; d < 5; ++d) {                  // dx = d-2
                acc[2 + d][i] = fmaf(f, X[1][2 + i + d], acc[2 + d][i]); // dy=1
                acc[7 + d][i] = fmaf(f, X[2][2 + i + d], acc[7 + d][i]); // dy=2
            }
        }
        if (edge) {
            float a = X[0][j0], c = X[0][j0 + 1];
            ex[0] = fmaf(a, a, ex[0]);
            ex[1] = fmaf(c, c, ex[1]);
        }
        if (ty == TYR - 1) {
            #pragma unroll
            for (int i = 0; i < 4; ++i) {
                float a = X[1][4 + i], c = X[2][4 + i];
                bh0[i] = fmaf(a, a, bh0[i]);
                bh1[i] = fmaf(c, c, bh1[i]);
            }
            if (edge) {
                float a = X[1][j0], c = X[1][j0 + 1];
                float d = X[2][j0], e = X[2][j0 + 1];
                bhe[0] = fmaf(a, a, bhe[0]);
                bhe[1] = fmaf(c, c, bhe[1]);
                bhe[2] = fmaf(d, d, bhe[2]);
                bhe[3] = fmaf(e, e, bhe[3]);
            }
        }
    };

    // ---- channel loop, double-buffered (static buffers, no runtime index) ----
    LOADW(XA, 0);
    #pragma unroll 1
    for (int ch = 0; ch < CCH - 2; ch += 2) {
        LOADW(XB, ch + 1);
        COMPW(XA);
        LOADW(XA, ch + 2);
        COMPW(XB);
    }
    LOADW(XB, CCH - 1);
    COMPW(XA);
    COMPW(XB);

    // ---- build packed label/mask tile ----
    for (int it = tid; it < PR * NSTR; it += TXG * TYR) {
        int r = it / NSTR, a = it - r * NSTR;
        int gy = y0 + r;
        int gx = x0 + a - 4;
        int pk = 0;
        if (gy < HH && gx >= 0 && gx < WW) {
            int g   = gt[((size_t)b * HH + gy) * WW + gx];
            int gb  = (g == 255) ? 0 : g;
            int s0v = seg[(((size_t)b * 2 + 0) * HH + gy) * WW + gx];
            int s1v = seg[(((size_t)b * 2 + 1) * HH + gy) * WW + gx];
            int s1c = (s1v == 255) ? 0 : s1v;
            bool bnd   = (gb * s1c) > 0;
            bool inter = (gy >= 2 && gy <= HH - 3 && gx >= 2 && gx <= WW - 3);
            pk = (bnd ? 1 : 0) | ((bnd && inter) ? 2 : 0)
               | ((s0v & 255) << 8) | ((s1v & 255) << 16);
        }
        pkT[it] = pk;
    }
    // ---- norm tile writes (disjoint cells) ----
    #pragma unroll
    for (int i = 0; i < 4; ++i)
        normArr[ty * NSTR + 4 * tx + 4 + i] = sqrtf(nrm[i]);
    if (edge) {
        int c0 = (tx == 0) ? 2 : 52;
        normArr[ty * NSTR + c0]     = sqrtf(ex[0]);
        normArr[ty * NSTR + c0 + 1] = sqrtf(ex[1]);
    }
    if (ty == TYR - 1) {
        #pragma unroll
        for (int i = 0; i < 4; ++i) {
            normArr[16 * NSTR + 4 * tx + 4 + i] = sqrtf(bh0[i]);
            normArr[17 * NSTR + 4 * tx + 4 + i] = sqrtf(bh1[i]);
        }
        if (edge) {
            int c0 = (tx == 0) ? 2 : 52;
            normArr[16 * NSTR + c0]     = sqrtf(bhe[0]);
            normArr[16 * NSTR + c0 + 1] = sqrtf(bhe[1]);
            normArr[17 * NSTR + c0]     = sqrtf(bhe[2]);
            normArr[17 * NSTR + c0 + 1] = sqrtf(bhe[3]);
        }
    }
    __syncthreads();

    // ---- pair epilogue (12-slot windows; own px at indices 4..7) ----
    float Sth = 0.f; int cth = 0, bth = 0;
    {
        const float* nr = &normArr[ty * NSTR + 4 * tx];
        const int*   pr = &pkT[ty * NSTR + 4 * tx];
        float n0[12], n1[12], n2[12];
        int   p0[12], p1[12], p2[12];
        #pragma unroll
        for (int jj = 0; jj < 3; ++jj) {
            *(float4*)&n0[4 * jj] = *(const float4*)(nr + 4 * jj);
            *(float4*)&n1[4 * jj] = *(const float4*)(nr + NSTR + 4 * jj);
            *(float4*)&n2[4 * jj] = *(const float4*)(nr + 2 * NSTR + 4 * jj);
            *(int4*)&p0[4 * jj] = *(const int4*)(pr + 4 * jj);
            *(int4*)&p1[4 * jj] = *(const int4*)(pr + NSTR + 4 * jj);
            *(int4*)&p2[4 * jj] = *(const int4*)(pr + 2 * NSTR + 4 * jj);
        }

        #pragma unroll
        for (int i = 0; i < 4; ++i) {
            int pkP  = p0[4 + i];
            int selP = (pkP >> 1) & 1;
            cth += selP;
            bth += pkP & 1;
            float nP = fmaxf(n0[4 + i], EPSQ);
            auto doPair = [&](float dot, int pkQ, float nQv) {
                int wgt = selP + ((pkQ >> 1) & 1);
                if (wgt) {
                    float lab = (float)(((pkP >> 8) & 255) * ((pkQ >> 8) & 255)
                                      + ((pkP >> 16) & 255) * ((pkQ >> 16) & 255));
                    float cs = dot / (nP * fmaxf(nQv, EPSQ));
                    float d  = cs - lab;
                    Sth = fmaf((float)wgt * d, d, Sth);
                }
            };
            doPair(acc[0][i], p0[5 + i], n0[5 + i]);
            doPair(acc[1][i], p0[6 + i], n0[6 + i]);
            #pragma unroll
            for (int d2 = 0; d2 < 5; ++d2) {
                doPair(acc[2 + d2][i], p1[2 + i + d2], n1[2 + i + d2]);
                doPair(acc[7 + d2][i], p2[2 + i + d2], n2[2 + i + d2]);
            }
        }
    }

    // ---- reduce + atomics (one per wave) ----
    #pragma unroll
    for (int off2 = 32; off2 > 0; off2 >>= 1) {
        Sth += __shfl_down(Sth, off2);
        cth += __shfl_down(cth, off2);
        bth += __shfl_down(bth, off2);
    }
    if ((tid & 63) == 0) {
        atomicAdd(&Ssum[b], Sth);
        atomicAdd(&cntArr[b], cth);
        atomicAdd(&bndArr[b], bth);
    }
}

__global__ void ctx_init(float* S, int* cnt, int* bnd) {
    int t = threadIdx.x;
    if (t < BB) { S[t] = 0.f; cnt[t] = 0; bnd[t] = 0; }
}

__global__ void ctx_finalize(const float* __restrict__ S, const int* __restrict__ cnt,
                             const int* __restrict__ bnd, float* __restrict__ out) {
    if (threadIdx.x == 0 && blockIdx.x == 0) {
        float tot = 0.f, nv = 0.f;
        for (int b = 0; b < BB; ++b) {
            if (bnd[b] >= 1) {
                float c = fmaxf((float)cnt[b], 1.f);
                tot += S[b] / (24.f * c);
                nv  += 1.f;
            }
        }
        tot = tot / fmaxf(nv, 1.f);
        if (isnan(tot)) tot = 0.f;
        out[0] = tot;
    }
}

extern "C" void kernel_launch(void* const* d_in, const int* in_sizes, int n_in,
                              void* d_out, int out_size, void* d_ws, size_t ws_size,
                              hipStream_t stream) {
    const float* er = (const float*)d_in[0];
    const int* seg  = (const int*)d_in[1];
    const int* gt   = (const int*)d_in[2];
    float* out = (float*)d_out;

    float* S   = (float*)d_ws;
    int*   cnt = (int*)d_ws + BB;
    int*   bnd = (int*)d_ws + 2 * BB;

    ctx_init<<<1, 64, 0, stream>>>(S, cnt, bnd);
    dim3 grid(WW / 48, HH / TYR, BB);
    dim3 block(TXG, TYR);
    ctx_main<<<grid, block, 0, stream>>>(er, seg, gt, S, cnt, bnd);
    ctx_finalize<<<1, 64, 0, stream>>>(S, cnt, bnd, out);
}